// Round 1
// baseline (115.981 us; speedup 1.0000x reference)
//
#include <hip/hip_runtime.h>
#include <math.h>

#define MARGIN 1.0f
#define N_MAX 1024

// ---------------- Kernel A: row squared norms ----------------
// grid = N blocks, 64 threads (one wave) per block; row per block.
__global__ __launch_bounds__(64) void row_norms_kernel(
    const float* __restrict__ f, float* __restrict__ sq, int D) {
  int row = blockIdx.x;
  int lane = threadIdx.x;
  const float4* fr = (const float4*)(f + (size_t)row * D);
  int D4 = D >> 2;
  float acc = 0.f;
  for (int c = lane; c < D4; c += 64) {
    float4 v = fr[c];
    acc += v.x * v.x + v.y * v.y + v.z * v.z + v.w * v.w;
  }
  for (int off = 32; off > 0; off >>= 1) acc += __shfl_down(acc, off, 64);
  if (lane == 0) sq[row] = acc;
}

// ---------------- Kernel B: pairwise distance matrix ----------------
// Tiled fp32 "GEMM": dist[i][j] = sqrt(max(sq_i + sq_j - 2*dot(f_i,f_j), 0))
// 64x64 tile per block, 256 threads, 4x4 micro-tile per thread, BK=16.
#define BK 16
__global__ __launch_bounds__(256) void dist_kernel(
    const float* __restrict__ f, const float* __restrict__ sq,
    float* __restrict__ dist, int N, int D) {
  __shared__ float As[BK][64 + 1];
  __shared__ float Bs[BK][64 + 1];

  const int tx = threadIdx.x & 15;   // 0..15
  const int ty = threadIdx.x >> 4;   // 0..15
  const int rowBase = blockIdx.y * 64;
  const int colBase = blockIdx.x * 64;

  float c[4][4] = {};

  for (int k0 = 0; k0 < D; k0 += BK) {
    // Stage 64xBK tiles of A (rows) and B (cols): 1024 elems each, 4 per thread.
#pragma unroll
    for (int i = 0; i < 4; ++i) {
      int li = threadIdx.x + i * 256;
      int r = li >> 4;
      int cc = li & 15;
      As[cc][r] = f[(size_t)(rowBase + r) * D + k0 + cc];
      Bs[cc][r] = f[(size_t)(colBase + r) * D + k0 + cc];
    }
    __syncthreads();
#pragma unroll
    for (int k = 0; k < BK; ++k) {
      float a[4], b[4];
#pragma unroll
      for (int m = 0; m < 4; ++m) a[m] = As[k][ty + 16 * m];
#pragma unroll
      for (int n = 0; n < 4; ++n) b[n] = Bs[k][tx + 16 * n];
#pragma unroll
      for (int m = 0; m < 4; ++m)
#pragma unroll
        for (int n = 0; n < 4; ++n) c[m][n] += a[m] * b[n];
    }
    __syncthreads();
  }

#pragma unroll
  for (int m = 0; m < 4; ++m) {
    int row = rowBase + ty + 16 * m;
    float sqr = sq[row];
#pragma unroll
    for (int n = 0; n < 4; ++n) {
      int col = colBase + tx + 16 * n;
      float d2 = sqr + sq[col] - 2.f * c[m][n];
      d2 = d2 > 0.f ? d2 : 0.f;
      dist[(size_t)row * N + col] = sqrtf(d2);
    }
  }
}

// ---------------- Kernel C: per-anchor triplet loss ----------------
// One block per anchor. Compact the anchor's distance row into pos/neg lists
// in LDS (avg |pos|~32, |neg|~992 => ~32K real pairs instead of 1M masked).
__global__ __launch_bounds__(256) void anchor_loss_kernel(
    const float* __restrict__ dist, const int* __restrict__ labels,
    float* __restrict__ partial, int N) {
  int i = blockIdx.x;
  __shared__ float dpos[N_MAX];
  __shared__ float dneg[N_MAX];
  __shared__ int cnt[2];
  __shared__ float red[4];

  if (threadIdx.x < 2) cnt[threadIdx.x] = 0;
  __syncthreads();

  int lab = labels[i];
  const float* drow = dist + (size_t)i * N;
  for (int j = threadIdx.x; j < N; j += 256) {
    float d = drow[j];
    if (labels[j] == lab) {
      dpos[atomicAdd(&cnt[0], 1)] = d;
    } else {
      dneg[atomicAdd(&cnt[1], 1)] = d;
    }
  }
  __syncthreads();

  int np = cnt[0], nn = cnt[1];
  float acc = 0.f;
  for (int p = 0; p < np; ++p) {
    float t = dpos[p] + MARGIN;
    for (int k = threadIdx.x; k < nn; k += 256) {
      float v = t - dneg[k];
      acc += (v > 0.f) ? v : 0.f;
    }
  }

  for (int off = 32; off > 0; off >>= 1) acc += __shfl_down(acc, off, 64);
  if ((threadIdx.x & 63) == 0) red[threadIdx.x >> 6] = acc;
  __syncthreads();
  if (threadIdx.x == 0) partial[i] = red[0] + red[1] + red[2] + red[3];
}

// ---------------- Kernel D: final reduction ----------------
__global__ __launch_bounds__(256) void final_reduce_kernel(
    const float* __restrict__ partial, float* __restrict__ out, int N) {
  float acc = 0.f;
  for (int j = threadIdx.x; j < N; j += 256) acc += partial[j];
  for (int off = 32; off > 0; off >>= 1) acc += __shfl_down(acc, off, 64);
  __shared__ float red[4];
  if ((threadIdx.x & 63) == 0) red[threadIdx.x >> 6] = acc;
  __syncthreads();
  if (threadIdx.x == 0) {
    double s = (double)red[0] + (double)red[1] + (double)red[2] + (double)red[3];
    out[0] = (float)(s / ((double)N + 1e-8));
  }
}

extern "C" void kernel_launch(void* const* d_in, const int* in_sizes, int n_in,
                              void* d_out, int out_size, void* d_ws, size_t ws_size,
                              hipStream_t stream) {
  const float* f = (const float*)d_in[0];
  const int* labels = (const int*)d_in[1];
  int N = in_sizes[1];           // 1024
  int D = in_sizes[0] / N;       // 512
  float* out = (float*)d_out;

  // ws layout: sq [N] | dist [N*N] | partial [N]
  float* sq = (float*)d_ws;
  float* dist = sq + N;
  float* partial = dist + (size_t)N * N;

  row_norms_kernel<<<N, 64, 0, stream>>>(f, sq, D);
  dim3 grid(N / 64, N / 64);
  dist_kernel<<<grid, 256, 0, stream>>>(f, sq, dist, N, D);
  anchor_loss_kernel<<<N, 256, 0, stream>>>(dist, labels, partial, N);
  final_reduce_kernel<<<1, 256, 0, stream>>>(partial, out, N);
}

// Round 2
// 90.761 us; speedup vs baseline: 1.2779x; 1.2779x over previous
//
#include <hip/hip_runtime.h>
#include <math.h>

#define MARGIN 1.0f
#define N_MAX 1024
#define BK 32
#define TSTR 68   // padded LDS row stride in floats (mult of 4 -> b128 aligned; 68%32=4 rotates banks)

// ---------------- Kernel B v2: pairwise distance matrix ----------------
// 64x64 tile, 256 threads, contiguous 4x4 micro-tile (b128 LDS reads),
// BK=32 with register double-buffered global staging. Row/col squared norms
// are accumulated in-kernel (kernel is LDS-BW bound; the extra FMAs are free).
__global__ __launch_bounds__(256) void dist_kernel(
    const float* __restrict__ f, float* __restrict__ dist, int N, int D) {
  __shared__ float As[BK][TSTR];
  __shared__ float Bs[BK][TSTR];

  const int tid = threadIdx.x;
  const int tx = tid & 15;         // col group 0..15
  const int ty = tid >> 4;         // row group 0..15
  const int rowBase = blockIdx.y * 64;
  const int colBase = blockIdx.x * 64;

  // staging mapping: idx = tid + 256*i ; r = idx>>3 (0..63), kc = idx&7 (float4 chunk)
  float4 aReg[2], bReg[2];

  const int r0 = tid >> 3;           // row for chunk 0
  const int r1 = (tid + 256) >> 3;   // row for chunk 1
  const int kc0 = (tid & 7) * 4;
  const int kc1 = kc0;               // (tid+256)&7 == tid&7

  auto loadTiles = [&](int k0) {
    aReg[0] = *(const float4*)(f + (size_t)(rowBase + r0) * D + k0 + kc0);
    aReg[1] = *(const float4*)(f + (size_t)(rowBase + r1) * D + k0 + kc1);
    bReg[0] = *(const float4*)(f + (size_t)(colBase + r0) * D + k0 + kc0);
    bReg[1] = *(const float4*)(f + (size_t)(colBase + r1) * D + k0 + kc1);
  };
  auto storeTiles = [&]() {
    As[kc0 + 0][r0] = aReg[0].x; As[kc0 + 1][r0] = aReg[0].y;
    As[kc0 + 2][r0] = aReg[0].z; As[kc0 + 3][r0] = aReg[0].w;
    As[kc1 + 0][r1] = aReg[1].x; As[kc1 + 1][r1] = aReg[1].y;
    As[kc1 + 2][r1] = aReg[1].z; As[kc1 + 3][r1] = aReg[1].w;
    Bs[kc0 + 0][r0] = bReg[0].x; Bs[kc0 + 1][r0] = bReg[0].y;
    Bs[kc0 + 2][r0] = bReg[0].z; Bs[kc0 + 3][r0] = bReg[0].w;
    Bs[kc1 + 0][r1] = bReg[1].x; Bs[kc1 + 1][r1] = bReg[1].y;
    Bs[kc1 + 2][r1] = bReg[1].z; Bs[kc1 + 3][r1] = bReg[1].w;
  };

  float c[4][4] = {};
  float asq[4] = {}, bsq[4] = {};

  loadTiles(0);
  for (int k0 = 0; k0 < D; k0 += BK) {
    __syncthreads();   // previous iteration's LDS reads done
    storeTiles();
    __syncthreads();   // tiles visible
    if (k0 + BK < D) loadTiles(k0 + BK);  // prefetch next chunk into registers

#pragma unroll
    for (int k = 0; k < BK; ++k) {
      float4 a = *(const float4*)&As[k][4 * ty];
      float4 b = *(const float4*)&Bs[k][4 * tx];
      float am[4] = {a.x, a.y, a.z, a.w};
      float bn[4] = {b.x, b.y, b.z, b.w};
#pragma unroll
      for (int m = 0; m < 4; ++m) asq[m] += am[m] * am[m];
#pragma unroll
      for (int n = 0; n < 4; ++n) bsq[n] += bn[n] * bn[n];
#pragma unroll
      for (int m = 0; m < 4; ++m)
#pragma unroll
        for (int n = 0; n < 4; ++n) c[m][n] += am[m] * bn[n];
    }
  }

#pragma unroll
  for (int m = 0; m < 4; ++m) {
    int row = rowBase + 4 * ty + m;
    float4 o;
    float* op = &o.x;
#pragma unroll
    for (int n = 0; n < 4; ++n) {
      float d2 = asq[m] + bsq[n] - 2.f * c[m][n];
      d2 = d2 > 0.f ? d2 : 0.f;
      op[n] = sqrtf(d2);
    }
    *(float4*)&dist[(size_t)row * N + colBase + 4 * tx] = o;
  }
}

// ---------------- Kernel C v2: per-anchor triplet loss ----------------
// One block per anchor. Wave-ballot compaction (1 atomic per wave per chunk,
// not per element). Pair loop: up to 4 neg distances live in registers,
// pos list broadcast-read from LDS -> ~3 VALU per pair.
__global__ __launch_bounds__(256) void anchor_loss_kernel(
    const float* __restrict__ dist, const int* __restrict__ labels,
    float* __restrict__ partial, int N) {
  const int i = blockIdx.x;
  const int tid = threadIdx.x;
  const int lane = tid & 63;

  __shared__ float dpos[N_MAX];   // stored as d + MARGIN
  __shared__ float dneg[N_MAX];
  __shared__ int cnt[2];
  __shared__ float red[4];

  if (tid < 2) cnt[tid] = 0;
  __syncthreads();

  const int lab = labels[i];
  const float* drow = dist + (size_t)i * N;

  for (int jb = 0; jb < N; jb += 256) {
    int j = jb + tid;
    bool valid = j < N;
    float d = valid ? drow[j] : 0.f;
    bool isPos = valid && (labels[j & (N_MAX - 1)] == lab);
    bool isNeg = valid && !isPos;

    unsigned long long mp = __ballot(isPos);
    unsigned long long mn = __ballot(isNeg);
    unsigned long long lt = (1ull << lane) - 1ull;

    int base_p = 0, base_n = 0;
    if (lane == 0) {
      base_p = atomicAdd(&cnt[0], __popcll(mp));
      base_n = atomicAdd(&cnt[1], __popcll(mn));
    }
    base_p = __shfl(base_p, 0, 64);
    base_n = __shfl(base_n, 0, 64);

    if (isPos) dpos[base_p + __popcll(mp & lt)] = d + MARGIN;
    if (isNeg) dneg[base_n + __popcll(mn & lt)] = d;
  }
  __syncthreads();

  const int np = cnt[0], nn = cnt[1];

  // Each thread owns up to 4 negatives in registers (nn <= 1024 = 4*256).
  float dk[4];
#pragma unroll
  for (int e = 0; e < 4; ++e) {
    int k = tid + 256 * e;
    dk[e] = (k < nn) ? dneg[k] : 1e30f;   // +INF pad -> relu term 0
  }

  float acc = 0.f;
  for (int p = 0; p < np; ++p) {
    float t = dpos[p];   // broadcast read (free)
#pragma unroll
    for (int e = 0; e < 4; ++e) {
      float v = t - dk[e];
      acc += (v > 0.f) ? v : 0.f;
    }
  }

  for (int off = 32; off > 0; off >>= 1) acc += __shfl_down(acc, off, 64);
  if (lane == 0) red[tid >> 6] = acc;
  __syncthreads();
  if (tid == 0) partial[i] = red[0] + red[1] + red[2] + red[3];
}

// ---------------- Kernel D: final reduction ----------------
__global__ __launch_bounds__(256) void final_reduce_kernel(
    const float* __restrict__ partial, float* __restrict__ out, int N) {
  float acc = 0.f;
  for (int j = threadIdx.x; j < N; j += 256) acc += partial[j];
  for (int off = 32; off > 0; off >>= 1) acc += __shfl_down(acc, off, 64);
  __shared__ float red[4];
  if ((threadIdx.x & 63) == 0) red[threadIdx.x >> 6] = acc;
  __syncthreads();
  if (threadIdx.x == 0) {
    double s = (double)red[0] + (double)red[1] + (double)red[2] + (double)red[3];
    out[0] = (float)(s / ((double)N + 1e-8));
  }
}

extern "C" void kernel_launch(void* const* d_in, const int* in_sizes, int n_in,
                              void* d_out, int out_size, void* d_ws, size_t ws_size,
                              hipStream_t stream) {
  const float* f = (const float*)d_in[0];
  const int* labels = (const int*)d_in[1];
  int N = in_sizes[1];           // 1024
  int D = in_sizes[0] / N;       // 512
  float* out = (float*)d_out;

  // ws layout: dist [N*N] | partial [N]
  float* dist = (float*)d_ws;
  float* partial = dist + (size_t)N * N;

  dim3 grid(N / 64, N / 64);
  dist_kernel<<<grid, 256, 0, stream>>>(f, dist, N, D);
  anchor_loss_kernel<<<N, 256, 0, stream>>>(dist, labels, partial, N);
  final_reduce_kernel<<<1, 256, 0, stream>>>(partial, out, N);
}

// Round 3
// 85.144 us; speedup vs baseline: 1.3622x; 1.0660x over previous
//
#include <hip/hip_runtime.h>
#include <math.h>

#define MARGIN 1.0f
#define N_MAX 1024
#define BK 64
#define LSTR 72   // LDS row stride in halfwords: 144 B rows (16B-aligned), 4*row%32 rotates banks

typedef short short8 __attribute__((ext_vector_type(8)));
typedef unsigned short ushort8 __attribute__((ext_vector_type(8)));
typedef float floatx16 __attribute__((ext_vector_type(16)));

__device__ inline unsigned short bf16_rne(float x) {
  unsigned u = __float_as_uint(x);
  unsigned r = (u + 0x7FFF + ((u >> 16) & 1)) >> 16;
  return (unsigned short)r;
}
__device__ inline float bf16_to_f32(unsigned short h) {
  return __uint_as_float(((unsigned)h) << 16);
}

// ---------------- Kernel A: fp32 -> bf16 hi/lo split + row squared norms ----
// One block (64 threads) per row of features [1024 x 512].
__global__ __launch_bounds__(64) void conv_kernel(
    const float* __restrict__ f, unsigned short* __restrict__ fhi,
    unsigned short* __restrict__ flo, float* __restrict__ sq, int D) {
  int row = blockIdx.x;
  int lane = threadIdx.x;
  const float* fr = f + (size_t)row * D;
  unsigned short* hr = fhi + (size_t)row * D;
  unsigned short* lr = flo + (size_t)row * D;

  float acc = 0.f;
  for (int c0 = lane * 4; c0 < D; c0 += 64 * 4) {
    float4 v = *(const float4*)(fr + c0);
    float xs[4] = {v.x, v.y, v.z, v.w};
    unsigned short hs[4], ls[4];
#pragma unroll
    for (int e = 0; e < 4; ++e) {
      float x = xs[e];
      acc += x * x;
      unsigned short h = bf16_rne(x);
      hs[e] = h;
      ls[e] = bf16_rne(x - bf16_to_f32(h));
    }
    *(ushort4*)(hr + c0) = make_ushort4(hs[0], hs[1], hs[2], hs[3]);
    *(ushort4*)(lr + c0) = make_ushort4(ls[0], ls[1], ls[2], ls[3]);
  }
  for (int off = 32; off > 0; off >>= 1) acc += __shfl_down(acc, off, 64);
  if (lane == 0) sq[row] = acc;
}

// ---------------- Kernel B v3: distance matrix via bf16 MFMA hi/lo ----------
// 64x64 tile per block, 256 threads = 4 waves, each wave one 32x32 MFMA tile.
// dot = hi*hi + hi*lo + lo*hi  (3x v_mfma_f32_32x32x16_bf16 per K16-step).
__global__ __launch_bounds__(256) void dist_kernel(
    const unsigned short* __restrict__ fhi, const unsigned short* __restrict__ flo,
    const float* __restrict__ sqv, float* __restrict__ dist, int N, int D) {
  __shared__ unsigned short Ah[64][LSTR];
  __shared__ unsigned short Al[64][LSTR];
  __shared__ unsigned short Bh[64][LSTR];
  __shared__ unsigned short Bl[64][LSTR];

  const int tid = threadIdx.x;
  const int rowBase = blockIdx.y * 64;
  const int colBase = blockIdx.x * 64;

  // staging mapping: row r = tid&63, k-chunk c = tid>>6 (16 bf16 each)
  const int sr = tid & 63;
  const int sc = (tid >> 6) * 16;

  // compute mapping: wave w -> 32x32 tile at (wr, wc)
  const int w = tid >> 6;
  const int lane = tid & 63;
  const int wr = (w >> 1) * 32;
  const int wc = (w & 1) * 32;
  const int arow = wr + (lane & 31);
  const int brow = wc + (lane & 31);
  const int kgrp = (lane >> 5) * 8;

  floatx16 acc = {};

  for (int k0 = 0; k0 < D; k0 += BK) {
    const size_t ga = (size_t)(rowBase + sr) * D + k0 + sc;
    const size_t gb = (size_t)(colBase + sr) * D + k0 + sc;
    ushort8 ah0 = *(const ushort8*)(fhi + ga);
    ushort8 ah1 = *(const ushort8*)(fhi + ga + 8);
    ushort8 al0 = *(const ushort8*)(flo + ga);
    ushort8 al1 = *(const ushort8*)(flo + ga + 8);
    ushort8 bh0 = *(const ushort8*)(fhi + gb);
    ushort8 bh1 = *(const ushort8*)(fhi + gb + 8);
    ushort8 bl0 = *(const ushort8*)(flo + gb);
    ushort8 bl1 = *(const ushort8*)(flo + gb + 8);
    __syncthreads();   // previous iteration's LDS reads done
    *(ushort8*)&Ah[sr][sc] = ah0; *(ushort8*)&Ah[sr][sc + 8] = ah1;
    *(ushort8*)&Al[sr][sc] = al0; *(ushort8*)&Al[sr][sc + 8] = al1;
    *(ushort8*)&Bh[sr][sc] = bh0; *(ushort8*)&Bh[sr][sc + 8] = bh1;
    *(ushort8*)&Bl[sr][sc] = bl0; *(ushort8*)&Bl[sr][sc + 8] = bl1;
    __syncthreads();   // tiles visible

#pragma unroll
    for (int kk = 0; kk < BK / 16; ++kk) {
      const int ko = kk * 16 + kgrp;
      short8 ahf = *(const short8*)&Ah[arow][ko];
      short8 alf = *(const short8*)&Al[arow][ko];
      short8 bhf = *(const short8*)&Bh[brow][ko];
      short8 blf = *(const short8*)&Bl[brow][ko];
      acc = __builtin_amdgcn_mfma_f32_32x32x16_bf16(ahf, bhf, acc, 0, 0, 0);
      acc = __builtin_amdgcn_mfma_f32_32x32x16_bf16(ahf, blf, acc, 0, 0, 0);
      acc = __builtin_amdgcn_mfma_f32_32x32x16_bf16(alf, bhf, acc, 0, 0, 0);
    }
  }

  // Epilogue: C/D layout col=lane&31, row=(reg&3)+8*(reg>>2)+4*(lane>>5)
  const int col = colBase + wc + (lane & 31);
  const float sqc = sqv[col];
#pragma unroll
  for (int r = 0; r < 16; ++r) {
    const int row = rowBase + wr + (r & 3) + 8 * (r >> 2) + 4 * (lane >> 5);
    float d2 = sqv[row] + sqc - 2.0f * acc[r];
    d2 = d2 > 0.f ? d2 : 0.f;
    dist[(size_t)row * N + col] = sqrtf(d2);
  }
}

// ---------------- Kernel C: per-anchor triplet loss (ballot compaction) ----
__global__ __launch_bounds__(256) void anchor_loss_kernel(
    const float* __restrict__ dist, const int* __restrict__ labels,
    float* __restrict__ partial, int N) {
  const int i = blockIdx.x;
  const int tid = threadIdx.x;
  const int lane = tid & 63;

  __shared__ float dpos[N_MAX];   // stored as d + MARGIN
  __shared__ float dneg[N_MAX];
  __shared__ int cnt[2];
  __shared__ float red[4];

  if (tid < 2) cnt[tid] = 0;
  __syncthreads();

  const int lab = labels[i];
  const float* drow = dist + (size_t)i * N;

  for (int jb = 0; jb < N; jb += 256) {
    int j = jb + tid;
    bool valid = j < N;
    float d = valid ? drow[j] : 0.f;
    bool isPos = valid && (labels[j & (N_MAX - 1)] == lab);
    bool isNeg = valid && !isPos;

    unsigned long long mp = __ballot(isPos);
    unsigned long long mn = __ballot(isNeg);
    unsigned long long lt = (1ull << lane) - 1ull;

    int base_p = 0, base_n = 0;
    if (lane == 0) {
      base_p = atomicAdd(&cnt[0], __popcll(mp));
      base_n = atomicAdd(&cnt[1], __popcll(mn));
    }
    base_p = __shfl(base_p, 0, 64);
    base_n = __shfl(base_n, 0, 64);

    if (isPos) dpos[base_p + __popcll(mp & lt)] = d + MARGIN;
    if (isNeg) dneg[base_n + __popcll(mn & lt)] = d;
  }
  __syncthreads();

  const int np = cnt[0], nn = cnt[1];

  float dk[4];
#pragma unroll
  for (int e = 0; e < 4; ++e) {
    int k = tid + 256 * e;
    dk[e] = (k < nn) ? dneg[k] : 1e30f;   // pad -> relu term 0
  }

  float accv = 0.f;
  for (int p = 0; p < np; ++p) {
    float t = dpos[p];
#pragma unroll
    for (int e = 0; e < 4; ++e) {
      float v = t - dk[e];
      accv += (v > 0.f) ? v : 0.f;
    }
  }

  for (int off = 32; off > 0; off >>= 1) accv += __shfl_down(accv, off, 64);
  if (lane == 0) red[tid >> 6] = accv;
  __syncthreads();
  if (tid == 0) partial[i] = red[0] + red[1] + red[2] + red[3];
}

// ---------------- Kernel D: final reduction ----------------
__global__ __launch_bounds__(256) void final_reduce_kernel(
    const float* __restrict__ partial, float* __restrict__ out, int N) {
  float acc = 0.f;
  for (int j = threadIdx.x; j < N; j += 256) acc += partial[j];
  for (int off = 32; off > 0; off >>= 1) acc += __shfl_down(acc, off, 64);
  __shared__ float red[4];
  if ((threadIdx.x & 63) == 0) red[threadIdx.x >> 6] = acc;
  __syncthreads();
  if (threadIdx.x == 0) {
    double s = (double)red[0] + (double)red[1] + (double)red[2] + (double)red[3];
    out[0] = (float)(s / ((double)N + 1e-8));
  }
}

extern "C" void kernel_launch(void* const* d_in, const int* in_sizes, int n_in,
                              void* d_out, int out_size, void* d_ws, size_t ws_size,
                              hipStream_t stream) {
  const float* f = (const float*)d_in[0];
  const int* labels = (const int*)d_in[1];
  int N = in_sizes[1];           // 1024
  int D = in_sizes[0] / N;       // 512
  float* out = (float*)d_out;

  // ws layout: fhi [N*D u16] | flo [N*D u16] | sq [N f32] | dist [N*N f32] | partial [N f32]
  unsigned short* fhi = (unsigned short*)d_ws;
  unsigned short* flo = fhi + (size_t)N * D;
  float* sq = (float*)(flo + (size_t)N * D);
  float* dist = sq + N;
  float* partial = dist + (size_t)N * N;

  conv_kernel<<<N, 64, 0, stream>>>(f, fhi, flo, sq, D);
  dim3 grid(N / 64, N / 64);
  dist_kernel<<<grid, 256, 0, stream>>>(fhi, flo, sq, dist, N, D);
  anchor_loss_kernel<<<N, 256, 0, stream>>>(dist, labels, partial, N);
  final_reduce_kernel<<<1, 256, 0, stream>>>(partial, out, N);
}

// Round 4
// 78.674 us; speedup vs baseline: 1.4742x; 1.0822x over previous
//
#include <hip/hip_runtime.h>
#include <math.h>

#define MARGIN 1.0f
#define N_MAX 1024
#define BK 64   // k-elements per staging iteration (8 chunks of 8)

typedef short short8 __attribute__((ext_vector_type(8)));
typedef unsigned short ushort8 __attribute__((ext_vector_type(8)));
typedef float floatx16 __attribute__((ext_vector_type(16)));

__device__ inline unsigned short bf16_rne(float x) {
  unsigned u = __float_as_uint(x);
  unsigned r = (u + 0x7FFF + ((u >> 16) & 1)) >> 16;
  return (unsigned short)r;
}
__device__ inline float bf16_to_f32(unsigned short h) {
  return __uint_as_float(((unsigned)h) << 16);
}

// ---------------- Kernel A: fp32 -> bf16 hi/lo split (CHUNKED layout) -------
// Chunked layout: F_c[kchunk][row][8]  (kchunk = k/8). This makes the dist
// kernel's staging fully coalesced AND its LDS accesses conflict-free.
// One block (64 threads) per row; lane t handles k-chunk t (D=512 -> 64 chunks).
__global__ __launch_bounds__(64) void conv_kernel(
    const float* __restrict__ f, unsigned short* __restrict__ fhi,
    unsigned short* __restrict__ flo, float* __restrict__ sq, int N, int D) {
  const int r = blockIdx.x;
  const int t = threadIdx.x;
  float acc = 0.f;
  if (t * 8 < D) {
    const float* src = f + (size_t)r * D + t * 8;
    float4 v0 = *(const float4*)(src);
    float4 v1 = *(const float4*)(src + 4);
    float xs[8] = {v0.x, v0.y, v0.z, v0.w, v1.x, v1.y, v1.z, v1.w};
    ushort8 hs, ls;
#pragma unroll
    for (int e = 0; e < 8; ++e) {
      float x = xs[e];
      acc += x * x;
      unsigned short h = bf16_rne(x);
      hs[e] = h;
      ls[e] = bf16_rne(x - bf16_to_f32(h));
    }
    const size_t off = ((size_t)t * N + r) * 8;   // [chunk][row][8]
    *(ushort8*)(fhi + off) = hs;
    *(ushort8*)(flo + off) = ls;
  }
  for (int off = 32; off > 0; off >>= 1) acc += __shfl_down(acc, off, 64);
  if (t == 0) sq[r] = acc;
}

// ---------------- Kernel B v4: distance matrix via bf16 MFMA hi/lo ----------
// 64x64 tile per block, 4 waves, each wave one 32x32 tile.
// LDS tiles [buf][array][chunk][row] of ushort8: staging writes are
// lane-sequential (conflict-free), fragment reads are 512B-contiguous
// (conflict-free). Double-buffered, ONE barrier per K-iteration, register
// prefetch of the next global chunk.
__global__ __launch_bounds__(256) void dist_kernel(
    const unsigned short* __restrict__ fhi, const unsigned short* __restrict__ flo,
    const float* __restrict__ sqv, float* __restrict__ dist, int N, int D) {
  // [2 bufs][4 arrays: Ah,Al,Bh,Bl][8 chunks][64 rows] of ushort8 = 64 KB
  __shared__ ushort8 T[2][4][8][64];

  const int tid = threadIdx.x;
  const int w = tid >> 6;          // wave 0..3
  const int lane = tid & 63;
  const int rowBase = blockIdx.y * 64;
  const int colBase = blockIdx.x * 64;

  const unsigned short* srcs[4] = {fhi, flo, fhi, flo};
  const int bases[4] = {rowBase, rowBase, colBase, colBase};

  // compute mapping: wave w -> 32x32 tile at (wr, wc)
  const int wr = (w >> 1) * 32;
  const int wc = (w & 1) * 32;
  const int m = lane & 31;
  const int h = lane >> 5;         // k-half selector

  ushort8 regs[8];

  // staging: wave w owns chunks {2w, 2w+1} of each of the 4 arrays.
  auto loadRegs = [&](int k0) {
    const int c0 = k0 >> 3;
#pragma unroll
    for (int s = 0; s < 8; ++s) {
      const int a = s >> 1;
      const int c = (w << 1) | (s & 1);
      regs[s] = *(const ushort8*)(srcs[a] + ((size_t)(c0 + c) * N + bases[a] + lane) * 8);
    }
  };
  auto storeRegs = [&](int b) {
#pragma unroll
    for (int s = 0; s < 8; ++s) {
      const int a = s >> 1;
      const int c = (w << 1) | (s & 1);
      T[b][a][c][lane] = regs[s];   // lane-sequential 16B -> conflict-free
    }
  };

  floatx16 acc = {};
  int b = 0;

  loadRegs(0);
  storeRegs(0);

  for (int k0 = 0; k0 < D; k0 += BK) {
    if (k0 + BK < D) loadRegs(k0 + BK);   // prefetch next into registers
    __syncthreads();                      // buffer b filled; prev reads done
#pragma unroll
    for (int kk = 0; kk < BK / 16; ++kk) {
      const int c = 2 * kk + h;
      short8 ahf = *(const short8*)&T[b][0][c][wr + m];
      short8 alf = *(const short8*)&T[b][1][c][wr + m];
      short8 bhf = *(const short8*)&T[b][2][c][wc + m];
      short8 blf = *(const short8*)&T[b][3][c][wc + m];
      acc = __builtin_amdgcn_mfma_f32_32x32x16_bf16(ahf, bhf, acc, 0, 0, 0);
      acc = __builtin_amdgcn_mfma_f32_32x32x16_bf16(ahf, blf, acc, 0, 0, 0);
      acc = __builtin_amdgcn_mfma_f32_32x32x16_bf16(alf, bhf, acc, 0, 0, 0);
    }
    if (k0 + BK < D) storeRegs(b ^ 1);    // fill other buffer (after compute)
    b ^= 1;
  }

  // Epilogue: C/D layout col=lane&31, row=(reg&3)+8*(reg>>2)+4*(lane>>5)
  const int col = colBase + wc + m;
  const float sqc = sqv[col];
#pragma unroll
  for (int r = 0; r < 16; ++r) {
    const int row = rowBase + wr + (r & 3) + 8 * (r >> 2) + 4 * h;
    float d2 = sqv[row] + sqc - 2.0f * acc[r];
    d2 = d2 > 0.f ? d2 : 0.f;
    dist[(size_t)row * N + col] = sqrtf(d2);
  }
}

// ---------------- Kernel C: per-anchor triplet loss (ballot compaction) ----
__global__ __launch_bounds__(256) void anchor_loss_kernel(
    const float* __restrict__ dist, const int* __restrict__ labels,
    float* __restrict__ partial, int N) {
  const int i = blockIdx.x;
  const int tid = threadIdx.x;
  const int lane = tid & 63;

  __shared__ float dpos[N_MAX];   // stored as d + MARGIN
  __shared__ float dneg[N_MAX];
  __shared__ int cnt[2];
  __shared__ float red[4];

  if (tid < 2) cnt[tid] = 0;
  __syncthreads();

  const int lab = labels[i];
  const float* drow = dist + (size_t)i * N;

  for (int jb = 0; jb < N; jb += 256) {
    int j = jb + tid;
    bool valid = j < N;
    float d = valid ? drow[j] : 0.f;
    bool isPos = valid && (labels[j & (N_MAX - 1)] == lab);
    bool isNeg = valid && !isPos;

    unsigned long long mp = __ballot(isPos);
    unsigned long long mn = __ballot(isNeg);
    unsigned long long lt = (1ull << lane) - 1ull;

    int base_p = 0, base_n = 0;
    if (lane == 0) {
      base_p = atomicAdd(&cnt[0], __popcll(mp));
      base_n = atomicAdd(&cnt[1], __popcll(mn));
    }
    base_p = __shfl(base_p, 0, 64);
    base_n = __shfl(base_n, 0, 64);

    if (isPos) dpos[base_p + __popcll(mp & lt)] = d + MARGIN;
    if (isNeg) dneg[base_n + __popcll(mn & lt)] = d;
  }
  __syncthreads();

  const int np = cnt[0], nn = cnt[1];

  float dk[4];
#pragma unroll
  for (int e = 0; e < 4; ++e) {
    int k = tid + 256 * e;
    dk[e] = (k < nn) ? dneg[k] : 1e30f;   // pad -> relu term 0
  }

  float accv = 0.f;
  for (int p = 0; p < np; ++p) {
    float t = dpos[p];
#pragma unroll
    for (int e = 0; e < 4; ++e) {
      float v = t - dk[e];
      accv += (v > 0.f) ? v : 0.f;
    }
  }

  for (int off = 32; off > 0; off >>= 1) accv += __shfl_down(accv, off, 64);
  if (lane == 0) red[tid >> 6] = accv;
  __syncthreads();
  if (tid == 0) partial[i] = red[0] + red[1] + red[2] + red[3];
}

// ---------------- Kernel D: final reduction ----------------
__global__ __launch_bounds__(256) void final_reduce_kernel(
    const float* __restrict__ partial, float* __restrict__ out, int N) {
  float acc = 0.f;
  for (int j = threadIdx.x; j < N; j += 256) acc += partial[j];
  for (int off = 32; off > 0; off >>= 1) acc += __shfl_down(acc, off, 64);
  __shared__ float red[4];
  if ((threadIdx.x & 63) == 0) red[threadIdx.x >> 6] = acc;
  __syncthreads();
  if (threadIdx.x == 0) {
    double s = (double)red[0] + (double)red[1] + (double)red[2] + (double)red[3];
    out[0] = (float)(s / ((double)N + 1e-8));
  }
}

extern "C" void kernel_launch(void* const* d_in, const int* in_sizes, int n_in,
                              void* d_out, int out_size, void* d_ws, size_t ws_size,
                              hipStream_t stream) {
  const float* f = (const float*)d_in[0];
  const int* labels = (const int*)d_in[1];
  int N = in_sizes[1];           // 1024
  int D = in_sizes[0] / N;       // 512
  float* out = (float*)d_out;

  // ws layout: fhi [N*D u16 chunked] | flo [N*D u16 chunked] | sq [N f32]
  //          | dist [N*N f32] | partial [N f32]
  unsigned short* fhi = (unsigned short*)d_ws;
  unsigned short* flo = fhi + (size_t)N * D;
  float* sq = (float*)(flo + (size_t)N * D);
  float* dist = sq + N;
  float* partial = dist + (size_t)N * N;

  conv_kernel<<<N, 64, 0, stream>>>(f, fhi, flo, sq, N, D);
  dim3 grid(N / 64, N / 64);
  dist_kernel<<<grid, 256, 0, stream>>>(fhi, flo, sq, dist, N, D);
  anchor_loss_kernel<<<N, 256, 0, stream>>>(dist, labels, partial, N);
  final_reduce_kernel<<<1, 256, 0, stream>>>(partial, out, N);
}